// Round 9
// baseline (385.933 us; speedup 1.0000x reference)
//
#include <hip/hip_runtime.h>

typedef __attribute__((ext_vector_type(8))) short bf16x8;
typedef __attribute__((ext_vector_type(4))) float f32x4;

#define GLD_LDS16(g, l)                                                        \
  __builtin_amdgcn_global_load_lds(                                            \
      (const __attribute__((address_space(1))) void*)(g),                      \
      (__attribute__((address_space(3))) void*)(l), 16, 0, 0)

__device__ __forceinline__ f32x4 mfma_bf16(bf16x8 a, bf16x8 b, f32x4 c) {
  return __builtin_amdgcn_mfma_f32_16x16x32_bf16(a, b, c, 0, 0, 0);
}

__device__ __forceinline__ unsigned short f2bf(float f) {
  union { float f; unsigned int u; } a;
  a.f = f;
  unsigned int u = a.u;
  unsigned int r = (u + 0x7fffu + ((u >> 16) & 1u)) >> 16;
  return (unsigned short)r;
}

__device__ __forceinline__ unsigned cvt_pk_bf16(float lo, float hi) {
  unsigned r;
  asm volatile("v_cvt_pk_bf16_f32 %0, %1, %2" : "=v"(r) : "v"(lo), "v"(hi));
  return r;
}

// ---------------- prep kernels ----------------

__global__ void k_convert(const float* __restrict__ in,
                          unsigned short* __restrict__ out, int n8) {
  int i = blockIdx.x * 256 + threadIdx.x;
  if (i >= n8) return;
  const float4* p = reinterpret_cast<const float4*>(in) + (size_t)i * 2;
  float4 a = p[0], b = p[1];
  union { unsigned short u[8]; uint4 v; } pk;
  pk.u[0] = f2bf(a.x); pk.u[1] = f2bf(a.y); pk.u[2] = f2bf(a.z); pk.u[3] = f2bf(a.w);
  pk.u[4] = f2bf(b.x); pk.u[5] = f2bf(b.y); pk.u[6] = f2bf(b.z); pk.u[7] = f2bf(b.w);
  reinterpret_cast<uint4*>(out)[i] = pk.v;
}

// out[c][r] = in[r][c], in: [R][C] f32, out: [C][R] bf16
__global__ void k_transpose(const float* __restrict__ in,
                            unsigned short* __restrict__ out, int R, int C) {
  __shared__ float tile[32][33];
  int c0 = blockIdx.x * 32, r0 = blockIdx.y * 32;
  int tx = threadIdx.x, ty = threadIdx.y;
#pragma unroll
  for (int j = 0; j < 4; ++j)
    tile[ty + j * 8][tx] = in[(size_t)(r0 + ty + j * 8) * C + (c0 + tx)];
  __syncthreads();
#pragma unroll
  for (int j = 0; j < 4; ++j)
    out[(size_t)(c0 + ty + j * 8) * R + (r0 + tx)] = f2bf(tile[tx][ty + j * 8]);
}

// vT[b][d][swz(k)] = V[b][k][d]; swizzle on 8-elem units within each 64-k chunk
__global__ void k_transpose_v(const unsigned short* __restrict__ qkv,
                              unsigned short* __restrict__ vT) {
  __shared__ unsigned short tile[32][33];
  int k0 = blockIdx.x * 32, d0 = blockIdx.y * 32, b = blockIdx.z;
  int tx = threadIdx.x, ty = threadIdx.y;
  const unsigned short* src = qkv + ((size_t)b * 2048 + k0) * 2304 + 2176 + d0;
#pragma unroll
  for (int j = 0; j < 4; ++j)
    tile[ty + j * 8][tx] = src[(size_t)(ty + j * 8) * 2304 + tx];
  __syncthreads();
#pragma unroll
  for (int j = 0; j < 4; ++j) {
    int d = d0 + ty + j * 8;
    int k = k0 + tx;
    int ks = (k & ~63) | (((((k >> 3) & 7) ^ (d & 7)) << 3)) | (k & 7);
    vT[(size_t)b * 262144 + (size_t)d * 2048 + ks] = tile[tx][ty + j * 8];
  }
}

__global__ void k_bias_concat(const float* __restrict__ bq,
                              const float* __restrict__ bk,
                              const float* __restrict__ bv,
                              float* __restrict__ o) {
  int i = blockIdx.x * 256 + threadIdx.x;
  if (i < 2048) o[i] = bq[i];
  else if (i < 2176) o[i] = bk[i - 2048];
  else if (i < 2304) o[i] = bv[i - 2176];
}

// ---------------- GEMM: C[M][N] = A[M][K] * Bt[N][K]^T + bias ----------------
// Depth-3 software pipeline: 4 LDS buffers, counted s_waitcnt vmcnt(8) (never
// 0 mid-loop) + raw s_barrier, so prefetch loads stay in flight across the
// barrier. XCD-aware block swizzle (grid % 8 == 0 for our launches).

template <bool OUT_F32>
__global__ __launch_bounds__(256, 2) void k_gemm(
    const unsigned short* __restrict__ A, const unsigned short* __restrict__ Bt,
    const float* __restrict__ bias, void* __restrict__ Cp, int M, int N, int K) {
  __shared__ __align__(16) unsigned short lda[4][128 * 32];
  __shared__ __align__(16) unsigned short ldb[4][128 * 32];
  const int t = threadIdx.x;
  const int l = t & 63;
  const int w = t >> 6;
  const int wr = w >> 1, wc = w & 1;
  const int lr = l & 15, lg = l >> 4;

  // XCD swizzle: contiguous chunks per XCD (nwg % 8 == 0)
  int gx = gridDim.x;
  int nwg = gx * gridDim.y;
  int lin = blockIdx.y * gx + blockIdx.x;
  int swz = (lin & 7) * (nwg >> 3) + (lin >> 3);
  const int m0 = (swz / gx) * 128, n0 = (swz % gx) * 128;

  // staging source coords (linear [128][32] tile layout)
  const int srow0 = t >> 2, scol = (t & 3) * 8;  // c=0 rows 0..63
  const size_t aBase = (size_t)(m0 + srow0) * K + scol;
  const size_t a2Base = (size_t)(m0 + srow0 + 64) * K + scol;
  const size_t bBase = (size_t)(n0 + srow0) * K + scol;
  const size_t b2Base = (size_t)(n0 + srow0 + 64) * K + scol;
  const int ldsOff = w * 512;  // wave-uniform dst base (HW adds lane*16B)

  f32x4 acc[4][4] = {};

#define STAGE_G(buf, kt)                                                       \
  do {                                                                         \
    GLD_LDS16(A + aBase + (kt), &lda[buf][0] + ldsOff);                        \
    GLD_LDS16(A + a2Base + (kt), &lda[buf][0] + 2048 + ldsOff);                \
    GLD_LDS16(Bt + bBase + (kt), &ldb[buf][0] + ldsOff);                       \
    GLD_LDS16(Bt + b2Base + (kt), &ldb[buf][0] + 2048 + ldsOff);               \
  } while (0)

  const int nsteps = K >> 5;  // K/32, >= 3
  STAGE_G(0, 0);
  STAGE_G(1, 32);
  STAGE_G(2, 64);

  for (int i = 0; i < nsteps; ++i) {
    if (i < nsteps - 2)
      asm volatile("s_waitcnt vmcnt(8)" ::: "memory");
    else if (i == nsteps - 2)
      asm volatile("s_waitcnt vmcnt(4)" ::: "memory");
    else
      asm volatile("s_waitcnt vmcnt(0)" ::: "memory");
    __builtin_amdgcn_s_barrier();  // step-i tile complete in all waves

    if (i + 3 < nsteps) STAGE_G((i + 3) & 3, (i + 3) * 32);

    const unsigned short* la = &lda[i & 3][0];
    const unsigned short* lb = &ldb[i & 3][0];
    bf16x8 af[4], bfr[4];
#pragma unroll
    for (int ii = 0; ii < 4; ++ii)
      af[ii] = *reinterpret_cast<const bf16x8*>(la + (wr * 64 + ii * 16 + lr) * 32 + lg * 8);
#pragma unroll
    for (int j = 0; j < 4; ++j)
      bfr[j] = *reinterpret_cast<const bf16x8*>(lb + (wc * 64 + j * 16 + lr) * 32 + lg * 8);
#pragma unroll
    for (int ii = 0; ii < 4; ++ii)
#pragma unroll
      for (int j = 0; j < 4; ++j)
        acc[ii][j] = mfma_bf16(af[ii], bfr[j], acc[ii][j]);
  }
#undef STAGE_G

#pragma unroll
  for (int j = 0; j < 4; ++j) {
    int col = n0 + wc * 64 + j * 16 + lr;
    float bv = bias[col];
#pragma unroll
    for (int i = 0; i < 4; ++i) {
      int rowb = m0 + wr * 64 + i * 16 + lg * 4;
#pragma unroll
      for (int r = 0; r < 4; ++r) {
        float v = acc[i][j][r] + bv;
        if (OUT_F32)
          reinterpret_cast<float*>(Cp)[(size_t)(rowb + r) * N + col] = v;
        else
          reinterpret_cast<unsigned short*>(Cp)[(size_t)(rowb + r) * N + col] = f2bf(v);
      }
    }
  }
}

// ---------------- flash attention ----------------
// qkv: [4096][2304] bf16; vT: [2][128][2048] bf16 (k pre-swizzled per 64-chunk)
// out: [4096][2048] bf16, layout [b*2048+s][h*128+d]
// K dbuf + V dbuf via global_load_lds; P swizzled; 1 barrier per chunk.

__global__ __launch_bounds__(512, 4) void k_attn(
    const unsigned short* __restrict__ qkv,
    const unsigned short* __restrict__ vT,
    unsigned short* __restrict__ out) {
  __shared__ __align__(16) unsigned short k_lds[2][64 * 128];  // 2x16KB, swizzled
  __shared__ __align__(16) unsigned short v_lds[2][128 * 64];  // 2x16KB, swizzled (from vT)
  __shared__ __align__(16) unsigned short p_lds[128 * 64];     // 16KB, swizzled

  const int t = threadIdx.x, l = t & 63, w = t >> 6;
  const int lr = l & 15, lg = l >> 4;
  const int bid = blockIdx.x;
  const int qt = bid & 15, h = (bid >> 4) & 15, b = bid >> 8;
  const size_t rowQ0 = (size_t)b * 2048 + qt * 128;
  const size_t rowK0 = (size_t)b * 2048;
  const unsigned short* vTb = vT + (size_t)b * 262144;

  // Q fragments direct from global (one-time): wave w owns q-rows w*16..w*16+15
  bf16x8 qf[4];
  {
    const unsigned short* qrow = qkv + (rowQ0 + w * 16 + lr) * 2304 + h * 128;
#pragma unroll
    for (int kd = 0; kd < 4; ++kd)
      qf[kd] = *reinterpret_cast<const bf16x8*>(qrow + kd * 32 + lg * 8);
  }

  // prologue: stage chunk 0 (K swizzled-source, V already swizzled in vT)
#pragma unroll
  for (int c = 0; c < 2; ++c) {
    int f16 = t + c * 512;
    int row = f16 >> 4;
    int col16 = (f16 & 15) ^ (row & 7);
    GLD_LDS16(qkv + (rowK0 + row) * 2304 + 2048 + col16 * 8,
              &k_lds[0][0] + w * 512 + c * 4096);
  }
#pragma unroll
  for (int c = 0; c < 2; ++c) {
    int unit = t + c * 512;
    int d = unit >> 3, u = unit & 7;
    GLD_LDS16(vTb + (size_t)d * 2048 + u * 8,
              &v_lds[0][0] + w * 512 + c * 4096);
  }
  __syncthreads();

  f32x4 o_acc[8] = {};
  float m_s = -1e30f, l_s = 0.f;  // per-lane stats for q-row (w*16+lr)

  const float C_SM = 0.08838834764831845f * 1.4426950408889634f;

  for (int kc = 0; kc < 32; ++kc) {
    const int cur = kc & 1;
    const unsigned short* kl = &k_lds[cur][0];
    const unsigned short* vl = &v_lds[cur][0];

    if (kc < 31) {
#pragma unroll
      for (int c = 0; c < 2; ++c) {
        int f16 = t + c * 512;
        int row = f16 >> 4;
        int col16 = (f16 & 15) ^ (row & 7);
        GLD_LDS16(qkv + (rowK0 + (kc + 1) * 64 + row) * 2304 + 2048 + col16 * 8,
                  &k_lds[cur ^ 1][0] + w * 512 + c * 4096);
      }
#pragma unroll
      for (int c = 0; c < 2; ++c) {
        int unit = t + c * 512;
        int d = unit >> 3, u = unit & 7;
        GLD_LDS16(vTb + (size_t)d * 2048 + (kc + 1) * 64 + u * 8,
                  &v_lds[cur ^ 1][0] + w * 512 + c * 4096);
      }
    }

    // S^T = K Q^T: sf[ctK][r] = S[q=w*16+lr][k = kc*64 + ctK*16 + lg*4 + r]
    f32x4 sf[4];
    __builtin_amdgcn_s_setprio(1);
#pragma unroll
    for (int ctK = 0; ctK < 4; ++ctK) {
      f32x4 s = {0.f, 0.f, 0.f, 0.f};
#pragma unroll
      for (int kd = 0; kd < 4; ++kd) {
        int row = ctK * 16 + lr;
        int u = (kd * 4 + lg) ^ (row & 7);
        bf16x8 kf = *reinterpret_cast<const bf16x8*>(kl + row * 128 + u * 8);
        s = mfma_bf16(kf, qf[kd], s);
      }
      sf[ctK] = s;
    }
    __builtin_amdgcn_s_setprio(0);

    // online softmax, in-lane row stats
    float vmax;
    {
      f32x4 m4 = sf[0];
#pragma unroll
      for (int ctK = 1; ctK < 4; ++ctK) {
        m4[0] = fmaxf(m4[0], sf[ctK][0]); m4[1] = fmaxf(m4[1], sf[ctK][1]);
        m4[2] = fmaxf(m4[2], sf[ctK][2]); m4[3] = fmaxf(m4[3], sf[ctK][3]);
      }
      vmax = fmaxf(fmaxf(m4[0], m4[1]), fmaxf(m4[2], m4[3]));
      vmax = fmaxf(vmax, __shfl_xor(vmax, 16));
      vmax = fmaxf(vmax, __shfl_xor(vmax, 32));
    }
    if (!__all(vmax <= m_s)) {
      float newm = fmaxf(m_s, vmax);
      float alpha = __builtin_amdgcn_exp2f((m_s - newm) * C_SM);
      m_s = newm;
      l_s *= alpha;
#pragma unroll
      for (int r = 0; r < 4; ++r) {
        float a_r = __shfl(alpha, lg * 4 + r);
#pragma unroll
        for (int ct8 = 0; ct8 < 8; ++ct8) o_acc[ct8][r] *= a_r;
      }
    }
    {
      float psum = 0.f;
#pragma unroll
      for (int ctK = 0; ctK < 4; ++ctK) {
#pragma unroll
        for (int r = 0; r < 4; ++r) {
          float p = __builtin_amdgcn_exp2f((sf[ctK][r] - m_s) * C_SM);
          sf[ctK][r] = p;
          psum += p;
        }
      }
      psum += __shfl_xor(psum, 16);
      psum += __shfl_xor(psum, 32);
      l_s += psum;
    }

    // write P (wave-private, swizzled): P[q=w*16+lr][k = ctK*16+lg*4+r]
#pragma unroll
    for (int ctK = 0; ctK < 4; ++ctK) {
      uint2 pk;
      pk.x = cvt_pk_bf16(sf[ctK][0], sf[ctK][1]);
      pk.y = cvt_pk_bf16(sf[ctK][2], sf[ctK][3]);
      *reinterpret_cast<uint2*>(
          p_lds + (w * 16 + lr) * 64 + ((ctK * 16 + lg * 4) ^ ((lr & 7) << 3))) = pk;
    }

    // O += P V (p slab wave-private -> no barrier between write and read)
    __builtin_amdgcn_s_setprio(1);
#pragma unroll
    for (int ks = 0; ks < 2; ++ks) {
      bf16x8 pf = *reinterpret_cast<const bf16x8*>(
          p_lds + (w * 16 + lr) * 64 + ((ks * 32 + lg * 8) ^ ((lr & 7) << 3)));
#pragma unroll
      for (int ct8 = 0; ct8 < 8; ++ct8) {
        bf16x8 vf = *reinterpret_cast<const bf16x8*>(
            vl + (ct8 * 16 + lr) * 64 + (((ks * 4 + lg) ^ (lr & 7)) * 8));
        o_acc[ct8] = mfma_bf16(pf, vf, o_acc[ct8]);
      }
    }
    __builtin_amdgcn_s_setprio(0);

    __syncthreads();  // drains vmcnt (next K/V staged) + protects cur bufs
  }

  // epilogue: normalize, write bf16
  float inv = 1.0f / l_s;
  float inv4[4];
#pragma unroll
  for (int r = 0; r < 4; ++r) inv4[r] = __shfl(inv, lg * 4 + r);
#pragma unroll
  for (int r = 0; r < 4; ++r) {
    size_t row = rowQ0 + w * 16 + lg * 4 + r;
#pragma unroll
    for (int ct8 = 0; ct8 < 8; ++ct8)
      out[row * 2048 + h * 128 + ct8 * 16 + lr] = f2bf(o_acc[ct8][r] * inv4[r]);
  }
}

// ---------------- launch ----------------

extern "C" void kernel_launch(void* const* d_in, const int* in_sizes, int n_in,
                              void* d_out, int out_size, void* d_ws,
                              size_t ws_size, hipStream_t stream) {
  const float* x  = (const float*)d_in[0];
  const float* wq = (const float*)d_in[2];
  const float* bq = (const float*)d_in[3];
  const float* wk = (const float*)d_in[4];
  const float* bk = (const float*)d_in[5];
  const float* wv = (const float*)d_in[6];
  const float* bv = (const float*)d_in[7];
  const float* wo = (const float*)d_in[8];
  const float* bo = (const float*)d_in[9];
  float* out = (float*)d_out;

  char* ws = (char*)d_ws;
  unsigned short* xb    = (unsigned short*)(ws);                       // 16.8MB [4096][2048] (reused as attn out)
  unsigned short* wqkvT = (unsigned short*)(ws + 16777216);            // 9.4MB  [2304][2048]
  unsigned short* woT   = (unsigned short*)(ws + 26214400);            // 8.4MB  [2048][2048]
  unsigned short* qkvb  = (unsigned short*)(ws + 34603008);            // 18.9MB [4096][2304]
  float*          biasq = (float*)(ws + 53477376);                     // 9.2KB
  unsigned short* vTb   = (unsigned short*)(ws + 53486592);            // 1.0MB  [2][128][2048]

  k_convert<<<4096, 256, 0, stream>>>(x, xb, 1048576);
  k_transpose<<<dim3(64, 64), dim3(32, 8), 0, stream>>>(wq, wqkvT, 2048, 2048);
  k_transpose<<<dim3(4, 64),  dim3(32, 8), 0, stream>>>(wk, wqkvT + (size_t)2048 * 2048, 2048, 128);
  k_transpose<<<dim3(4, 64),  dim3(32, 8), 0, stream>>>(wv, wqkvT + (size_t)2176 * 2048, 2048, 128);
  k_transpose<<<dim3(64, 64), dim3(32, 8), 0, stream>>>(wo, woT, 2048, 2048);
  k_bias_concat<<<9, 256, 0, stream>>>(bq, bk, bv, biasq);

  k_gemm<false><<<dim3(18, 32), 256, 0, stream>>>(xb, wqkvT, biasq, qkvb, 4096, 2304, 2048);
  k_transpose_v<<<dim3(64, 4, 2), dim3(32, 8), 0, stream>>>(qkvb, vTb);
  k_attn<<<512, 512, 0, stream>>>(qkvb, vTb, xb);
  k_gemm<true><<<dim3(16, 32), 256, 0, stream>>>(xb, woT, bo, out, 4096, 2048, 2048);
}

// Round 11
// 374.084 us; speedup vs baseline: 1.0317x; 1.0317x over previous
//
#include <hip/hip_runtime.h>

typedef __attribute__((ext_vector_type(8))) short bf16x8;
typedef __attribute__((ext_vector_type(4))) float f32x4;

#define GLD_LDS16(g, l)                                                        \
  __builtin_amdgcn_global_load_lds(                                            \
      (const __attribute__((address_space(1))) void*)(g),                      \
      (__attribute__((address_space(3))) void*)(l), 16, 0, 0)

__device__ __forceinline__ f32x4 mfma_bf16(bf16x8 a, bf16x8 b, f32x4 c) {
  return __builtin_amdgcn_mfma_f32_16x16x32_bf16(a, b, c, 0, 0, 0);
}

__device__ __forceinline__ unsigned short f2bf(float f) {
  union { float f; unsigned int u; } a;
  a.f = f;
  unsigned int u = a.u;
  unsigned int r = (u + 0x7fffu + ((u >> 16) & 1u)) >> 16;
  return (unsigned short)r;
}

__device__ __forceinline__ unsigned cvt_pk_bf16(float lo, float hi) {
  unsigned r;
  asm volatile("v_cvt_pk_bf16_f32 %0, %1, %2" : "=v"(r) : "v"(lo), "v"(hi));
  return r;
}

// ---------------- prep kernels ----------------

__global__ void k_convert(const float* __restrict__ in,
                          unsigned short* __restrict__ out, int n8) {
  int i = blockIdx.x * 256 + threadIdx.x;
  if (i >= n8) return;
  const float4* p = reinterpret_cast<const float4*>(in) + (size_t)i * 2;
  float4 a = p[0], b = p[1];
  union { unsigned short u[8]; uint4 v; } pk;
  pk.u[0] = f2bf(a.x); pk.u[1] = f2bf(a.y); pk.u[2] = f2bf(a.z); pk.u[3] = f2bf(a.w);
  pk.u[4] = f2bf(b.x); pk.u[5] = f2bf(b.y); pk.u[6] = f2bf(b.z); pk.u[7] = f2bf(b.w);
  reinterpret_cast<uint4*>(out)[i] = pk.v;
}

// out[c][r] = in[r][c], in: [R][C] f32, out: [C][R] bf16
__global__ void k_transpose(const float* __restrict__ in,
                            unsigned short* __restrict__ out, int R, int C) {
  __shared__ float tile[32][33];
  int c0 = blockIdx.x * 32, r0 = blockIdx.y * 32;
  int tx = threadIdx.x, ty = threadIdx.y;
#pragma unroll
  for (int j = 0; j < 4; ++j)
    tile[ty + j * 8][tx] = in[(size_t)(r0 + ty + j * 8) * C + (c0 + tx)];
  __syncthreads();
#pragma unroll
  for (int j = 0; j < 4; ++j)
    out[(size_t)(c0 + ty + j * 8) * R + (r0 + tx)] = f2bf(tile[tx][ty + j * 8]);
}

// vT[b][d][swz(k)] = V[b][k][d]; swizzle on 8-elem units within each 64-k chunk
__global__ void k_transpose_v(const unsigned short* __restrict__ qkv,
                              unsigned short* __restrict__ vT) {
  __shared__ unsigned short tile[32][33];
  int k0 = blockIdx.x * 32, d0 = blockIdx.y * 32, b = blockIdx.z;
  int tx = threadIdx.x, ty = threadIdx.y;
  const unsigned short* src = qkv + ((size_t)b * 2048 + k0) * 2304 + 2176 + d0;
#pragma unroll
  for (int j = 0; j < 4; ++j)
    tile[ty + j * 8][tx] = src[(size_t)(ty + j * 8) * 2304 + tx];
  __syncthreads();
#pragma unroll
  for (int j = 0; j < 4; ++j) {
    int d = d0 + ty + j * 8;
    int k = k0 + tx;
    int ks = (k & ~63) | (((((k >> 3) & 7) ^ (d & 7)) << 3)) | (k & 7);
    vT[(size_t)b * 262144 + (size_t)d * 2048 + ks] = tile[tx][ty + j * 8];
  }
}

__global__ void k_bias_concat(const float* __restrict__ bq,
                              const float* __restrict__ bk,
                              const float* __restrict__ bv,
                              float* __restrict__ o) {
  int i = blockIdx.x * 256 + threadIdx.x;
  if (i < 2048) o[i] = bq[i];
  else if (i < 2176) o[i] = bk[i - 2048];
  else if (i < 2304) o[i] = bv[i - 2176];
}

// ---------------- GEMM: C[M][N] = A[M][K] * Bt[N][K]^T + bias ----------------
// 128x64 tile, BK=32, 2-phase dbuf (stage-next before compute, 1 barrier/step).
// Smaller tile -> 4.5 blocks/CU (QKV) for TLP + tail balance; all L3-resident.

template <bool OUT_F32>
__global__ __launch_bounds__(256, 4) void k_gemm(
    const unsigned short* __restrict__ A, const unsigned short* __restrict__ Bt,
    const float* __restrict__ bias, void* __restrict__ Cp, int M, int N, int K) {
  __shared__ __align__(16) unsigned short lda[2][128 * 32];
  __shared__ __align__(16) unsigned short ldb[2][64 * 32];
  const int t = threadIdx.x;
  const int l = t & 63;
  const int w = t >> 6;
  const int wr = w >> 1, wc = w & 1;
  const int lr = l & 15, lg = l >> 4;

  // XCD swizzle: contiguous chunks per XCD (nwg % 8 == 0)
  int gx = gridDim.x;
  int nwg = gx * gridDim.y;
  int lin = blockIdx.y * gx + blockIdx.x;
  int swz = (lin & 7) * (nwg >> 3) + (lin >> 3);
  const int m0 = (swz / gx) * 128, n0 = (swz % gx) * 64;

  // staging source coords (linear [rows][32] tile layout)
  const int srow0 = t >> 2, scol = (t & 3) * 8;
  const size_t aBase = (size_t)(m0 + srow0) * K + scol;
  const size_t a2Base = (size_t)(m0 + srow0 + 64) * K + scol;
  const size_t bBase = (size_t)(n0 + srow0) * K + scol;
  const int ldsOff = w * 512;  // wave-uniform dst base (HW adds lane*16B)

  f32x4 acc[4][2] = {};

#define STAGE_G(buf, kt)                                                       \
  do {                                                                         \
    GLD_LDS16(A + aBase + (kt), &lda[buf][0] + ldsOff);                        \
    GLD_LDS16(A + a2Base + (kt), &lda[buf][0] + 2048 + ldsOff);                \
    GLD_LDS16(Bt + bBase + (kt), &ldb[buf][0] + ldsOff);                       \
  } while (0)

  STAGE_G(0, 0);
  __syncthreads();

  int cur = 0;
  for (int kt = 32; kt < K; kt += 32) {
    STAGE_G(cur ^ 1, kt);
    bf16x8 af[4], bfr[2];
#pragma unroll
    for (int i = 0; i < 4; ++i)
      af[i] = *reinterpret_cast<const bf16x8*>(&lda[cur][0] + (wr * 64 + i * 16 + lr) * 32 + lg * 8);
#pragma unroll
    for (int j = 0; j < 2; ++j)
      bfr[j] = *reinterpret_cast<const bf16x8*>(&ldb[cur][0] + (wc * 32 + j * 16 + lr) * 32 + lg * 8);
#pragma unroll
    for (int i = 0; i < 4; ++i)
#pragma unroll
      for (int j = 0; j < 2; ++j)
        acc[i][j] = mfma_bf16(af[i], bfr[j], acc[i][j]);
    __syncthreads();
    cur ^= 1;
  }
  {
    bf16x8 af[4], bfr[2];
#pragma unroll
    for (int i = 0; i < 4; ++i)
      af[i] = *reinterpret_cast<const bf16x8*>(&lda[cur][0] + (wr * 64 + i * 16 + lr) * 32 + lg * 8);
#pragma unroll
    for (int j = 0; j < 2; ++j)
      bfr[j] = *reinterpret_cast<const bf16x8*>(&ldb[cur][0] + (wc * 32 + j * 16 + lr) * 32 + lg * 8);
#pragma unroll
    for (int i = 0; i < 4; ++i)
#pragma unroll
      for (int j = 0; j < 2; ++j)
        acc[i][j] = mfma_bf16(af[i], bfr[j], acc[i][j]);
  }
#undef STAGE_G

#pragma unroll
  for (int j = 0; j < 2; ++j) {
    int col = n0 + wc * 32 + j * 16 + lr;
    float bv = bias[col];
#pragma unroll
    for (int i = 0; i < 4; ++i) {
      int rowb = m0 + wr * 64 + i * 16 + lg * 4;
#pragma unroll
      for (int r = 0; r < 4; ++r) {
        float v = acc[i][j][r] + bv;
        if (OUT_F32)
          reinterpret_cast<float*>(Cp)[(size_t)(rowb + r) * N + col] = v;
        else
          reinterpret_cast<unsigned short*>(Cp)[(size_t)(rowb + r) * N + col] = f2bf(v);
      }
    }
  }
}

// ---------------- flash attention ----------------
// QBLK=256: 8 waves x 32 q-rows -> K/V LDS reads amortized over 2x q-rows.
// qkv: [4096][2304] bf16; vT: [2][128][2048] bf16 (k pre-swizzled per 64-chunk)
// out: [4096][2048] bf16; grid 256 blocks (1/CU exact).

__global__ __launch_bounds__(512, 2) void k_attn(
    const unsigned short* __restrict__ qkv,
    const unsigned short* __restrict__ vT,
    unsigned short* __restrict__ out) {
  __shared__ __align__(16) unsigned short k_lds[2][64 * 128];  // 2x16KB, swizzled
  __shared__ __align__(16) unsigned short v_lds[2][128 * 64];  // 2x16KB, swizzled (from vT)
  __shared__ __align__(16) unsigned short p_lds[256 * 64];     // 32KB, swizzled

  const int t = threadIdx.x, l = t & 63, w = t >> 6;
  const int lr = l & 15, lg = l >> 4;
  const int bid = blockIdx.x;
  const int qt = bid & 7, h = (bid >> 3) & 15, b = bid >> 7;
  const size_t rowQ0 = (size_t)b * 2048 + qt * 256;
  const size_t rowK0 = (size_t)b * 2048;
  const unsigned short* vTb = vT + (size_t)b * 262144;

  // Q fragments direct from global: wave w owns q-rows w*32 .. w*32+31
  bf16x8 qf[2][4];
#pragma unroll
  for (int rt = 0; rt < 2; ++rt) {
    const unsigned short* qrow =
        qkv + (rowQ0 + w * 32 + rt * 16 + lr) * 2304 + h * 128;
#pragma unroll
    for (int kd = 0; kd < 4; ++kd)
      qf[rt][kd] = *reinterpret_cast<const bf16x8*>(qrow + kd * 32 + lg * 8);
  }

  // prologue: stage chunk 0 (K swizzled-source, V already swizzled in vT)
#pragma unroll
  for (int c = 0; c < 2; ++c) {
    int f16 = t + c * 512;
    int row = f16 >> 4;
    int col16 = (f16 & 15) ^ (row & 7);
    GLD_LDS16(qkv + (rowK0 + row) * 2304 + 2048 + col16 * 8,
              &k_lds[0][0] + w * 512 + c * 4096);
  }
#pragma unroll
  for (int c = 0; c < 2; ++c) {
    int unit = t + c * 512;
    int d = unit >> 3, u = unit & 7;
    GLD_LDS16(vTb + (size_t)d * 2048 + u * 8,
              &v_lds[0][0] + w * 512 + c * 4096);
  }
  __syncthreads();

  f32x4 o_acc[2][8] = {};
  float m_s[2] = {-1e30f, -1e30f}, l_s[2] = {0.f, 0.f};

  const float C_SM = 0.08838834764831845f * 1.4426950408889634f;

  for (int kc = 0; kc < 32; ++kc) {
    const int cur = kc & 1;
    const unsigned short* kl = &k_lds[cur][0];
    const unsigned short* vl = &v_lds[cur][0];

    if (kc < 31) {
#pragma unroll
      for (int c = 0; c < 2; ++c) {
        int f16 = t + c * 512;
        int row = f16 >> 4;
        int col16 = (f16 & 15) ^ (row & 7);
        GLD_LDS16(qkv + (rowK0 + (kc + 1) * 64 + row) * 2304 + 2048 + col16 * 8,
                  &k_lds[cur ^ 1][0] + w * 512 + c * 4096);
      }
#pragma unroll
      for (int c = 0; c < 2; ++c) {
        int unit = t + c * 512;
        int d = unit >> 3, u = unit & 7;
        GLD_LDS16(vTb + (size_t)d * 2048 + (kc + 1) * 64 + u * 8,
                  &v_lds[cur ^ 1][0] + w * 512 + c * 4096);
      }
    }

    // S^T = K Q^T: sf[rt][ctK][r] = S[q=w*32+rt*16+lr][k = kc*64+ctK*16+lg*4+r]
    // kf shared across both q-sets -> K LDS reads amortized 2x.
    f32x4 sf[2][4];
    __builtin_amdgcn_s_setprio(1);
#pragma unroll
    for (int ctK = 0; ctK < 4; ++ctK) {
      f32x4 s0 = {0.f, 0.f, 0.f, 0.f}, s1 = {0.f, 0.f, 0.f, 0.f};
#pragma unroll
      for (int kd = 0; kd < 4; ++kd) {
        int row = ctK * 16 + lr;
        int u = (kd * 4 + lg) ^ (row & 7);
        bf16x8 kf = *reinterpret_cast<const bf16x8*>(kl + row * 128 + u * 8);
        s0 = mfma_bf16(kf, qf[0][kd], s0);
        s1 = mfma_bf16(kf, qf[1][kd], s1);
      }
      sf[0][ctK] = s0; sf[1][ctK] = s1;
    }
    __builtin_amdgcn_s_setprio(0);

    // online softmax, in-lane row stats (per rt)
#pragma unroll
    for (int rt = 0; rt < 2; ++rt) {
      float vmax;
      {
        f32x4 m4 = sf[rt][0];
#pragma unroll
        for (int ctK = 1; ctK < 4; ++ctK) {
          m4[0] = fmaxf(m4[0], sf[rt][ctK][0]); m4[1] = fmaxf(m4[1], sf[rt][ctK][1]);
          m4[2] = fmaxf(m4[2], sf[rt][ctK][2]); m4[3] = fmaxf(m4[3], sf[rt][ctK][3]);
        }
        vmax = fmaxf(fmaxf(m4[0], m4[1]), fmaxf(m4[2], m4[3]));
        vmax = fmaxf(vmax, __shfl_xor(vmax, 16));
        vmax = fmaxf(vmax, __shfl_xor(vmax, 32));
      }
      if (!__all(vmax <= m_s[rt])) {
        float newm = fmaxf(m_s[rt], vmax);
        float alpha = __builtin_amdgcn_exp2f((m_s[rt] - newm) * C_SM);
        m_s[rt] = newm;
        l_s[rt] *= alpha;
#pragma unroll
        for (int r = 0; r < 4; ++r) {
          float a_r = __shfl(alpha, lg * 4 + r);
#pragma unroll
          for (int ct8 = 0; ct8 < 8; ++ct8) o_acc[rt][ct8][r] *= a_r;
        }
      }
      {
        float psum = 0.f;
#pragma unroll
        for (int ctK = 0; ctK < 4; ++ctK) {
#pragma unroll
          for (int r = 0; r < 4; ++r) {
            float p = __builtin_amdgcn_exp2f((sf[rt][ctK][r] - m_s[rt]) * C_SM);
            sf[rt][ctK][r] = p;
            psum += p;
          }
        }
        psum += __shfl_xor(psum, 16);
        psum += __shfl_xor(psum, 32);
        l_s[rt] += psum;
      }
      // write P (wave-private, swizzled)
#pragma unroll
      for (int ctK = 0; ctK < 4; ++ctK) {
        uint2 pk;
        pk.x = cvt_pk_bf16(sf[rt][ctK][0], sf[rt][ctK][1]);
        pk.y = cvt_pk_bf16(sf[rt][ctK][2], sf[rt][ctK][3]);
        *reinterpret_cast<uint2*>(
            p_lds + (w * 32 + rt * 16 + lr) * 64 +
            ((ctK * 16 + lg * 4) ^ ((lr & 7) << 3))) = pk;
      }
    }

    // O += P V; vf shared across both q-sets -> V LDS reads amortized 2x.
    __builtin_amdgcn_s_setprio(1);
#pragma unroll
    for (int ks = 0; ks < 2; ++ks) {
      bf16x8 pf0 = *reinterpret_cast<const bf16x8*>(
          p_lds + (w * 32 + lr) * 64 + ((ks * 32 + lg * 8) ^ ((lr & 7) << 3)));
      bf16x8 pf1 = *reinterpret_cast<const bf16x8*>(
          p_lds + (w * 32 + 16 + lr) * 64 + ((ks * 32 + lg * 8) ^ ((lr & 7) << 3)));
#pragma unroll
      for (int ct8 = 0; ct8 < 8; ++ct8) {
        bf16x8 vf = *reinterpret_cast<const bf16x8*>(
            vl + (ct8 * 16 + lr) * 64 + (((ks * 4 + lg) ^ (lr & 7)) * 8));
        o_acc[0][ct8] = mfma_bf16(pf0, vf, o_acc[0][ct8]);
        o_acc[1][ct8] = mfma_bf16(pf1, vf, o_acc[1][ct8]);
      }
    }
    __builtin_amdgcn_s_setprio(0);

    __syncthreads();  // next K/V staged + cur bufs free
  }

  // epilogue: normalize, write bf16
#pragma unroll
  for (int rt = 0; rt < 2; ++rt) {
    float inv = 1.0f / l_s[rt];
    float inv4[4];
#pragma unroll
    for (int r = 0; r < 4; ++r) inv4[r] = __shfl(inv, lg * 4 + r);
#pragma unroll
    for (int r = 0; r < 4; ++r) {
      size_t row = rowQ0 + w * 32 + rt * 16 + lg * 4 + r;
#pragma unroll
      for (int ct8 = 0; ct8 < 8; ++ct8)
        out[row * 2048 + h * 128 + ct8 * 16 + lr] = f2bf(o_acc[rt][ct8][r] * inv4[r]);
    }
  }
}

// ---------------- launch ----------------

extern "C" void kernel_launch(void* const* d_in, const int* in_sizes, int n_in,
                              void* d_out, int out_size, void* d_ws,
                              size_t ws_size, hipStream_t stream) {
  const float* x  = (const float*)d_in[0];
  const float* wq = (const float*)d_in[2];
  const float* bq = (const float*)d_in[3];
  const float* wk = (const float*)d_in[4];
  const float* bk = (const float*)d_in[5];
  const float* wv = (const float*)d_in[6];
  const float* bv = (const float*)d_in[7];
  const float* wo = (const float*)d_in[8];
  const float* bo = (const float*)d_in[9];
  float* out = (float*)d_out;

  char* ws = (char*)d_ws;
  unsigned short* xb    = (unsigned short*)(ws);                       // 16.8MB [4096][2048] (reused as attn out)
  unsigned short* wqkvT = (unsigned short*)(ws + 16777216);            // 9.4MB  [2304][2048]
  unsigned short* woT   = (unsigned short*)(ws + 26214400);            // 8.4MB  [2048][2048]
  unsigned short* qkvb  = (unsigned short*)(ws + 34603008);            // 18.9MB [4096][2304]
  float*          biasq = (float*)(ws + 53477376);                     // 9.2KB
  unsigned short* vTb   = (unsigned short*)(ws + 53486592);            // 1.0MB  [2][128][2048]

  k_convert<<<4096, 256, 0, stream>>>(x, xb, 1048576);
  k_transpose<<<dim3(64, 64), dim3(32, 8), 0, stream>>>(wq, wqkvT, 2048, 2048);
  k_transpose<<<dim3(4, 64),  dim3(32, 8), 0, stream>>>(wk, wqkvT + (size_t)2048 * 2048, 2048, 128);
  k_transpose<<<dim3(4, 64),  dim3(32, 8), 0, stream>>>(wv, wqkvT + (size_t)2176 * 2048, 2048, 128);
  k_transpose<<<dim3(64, 64), dim3(32, 8), 0, stream>>>(wo, woT, 2048, 2048);
  k_bias_concat<<<9, 256, 0, stream>>>(bq, bk, bv, biasq);

  k_gemm<false><<<dim3(36, 32), 256, 0, stream>>>(xb, wqkvT, biasq, qkvb, 4096, 2304, 2048);
  k_transpose_v<<<dim3(64, 4, 2), dim3(32, 8), 0, stream>>>(qkvb, vTb);
  k_attn<<<256, 512, 0, stream>>>(qkvb, vTb, xb);
  k_gemm<true><<<dim3(32, 32), 256, 0, stream>>>(xb, woT, bo, out, 4096, 2048, 2048);
}